// Round 3
// baseline (546.647 us; speedup 1.0000x reference)
//
#include <hip/hip_runtime.h>

// ContactNet grasp construction — memory-bound elementwise kernel.
// Inputs (fp32): points[N,3], z1[N,3], z2[N,3], s[N], w[N]
// Outputs (fp32, concatenated flat): points[N*3] | grasps[N*16] | sigmoid(s)[N] | relu(w)[N]
//
// Dtype forensics:
//  R0 (bf16 in): NaN in pure-copy output -> inputs are fp32 (fp32 mantissa bits
//     decode to bf16 NaN at ~1/256 rate).
//  R2 (bf16 out): Output-0 absmax 7.265625 == sqrt(2)*5.14 = expected max of
//     |points[2i+1]-points[i]| (N(0,2) max over 6.3M) -> output buffer is fp32,
//     our packed-bf16 halves were being read as fp32. => fp32 in, fp32 out.

typedef float floatx4 __attribute__((ext_vector_type(4)));

constexpr long N_POINTS    = 4194304;
constexpr long GRASP_BASE4 = N_POINTS * 3 / 4;    // float4 index of grasps section
constexpr long S_BASE4     = N_POINTS * 19 / 4;   // float4 index of sigmoid(s) section
constexpr long W_BASE4     = N_POINTS * 20 / 4;   // float4 index of relu(w) section

// fp32 element `idx` (flat within the thread's 12-element group) from a floatx4[3] bundle
#define GETF(arr, idx) (arr[(idx) >> 2][(idx) & 3])

__global__ __launch_bounds__(256) void contactnet_kernel(
    const floatx4* __restrict__ pts,
    const floatx4* __restrict__ z1v,
    const floatx4* __restrict__ z2v,
    const floatx4* __restrict__ sv,
    const floatx4* __restrict__ wv,
    floatx4* __restrict__ out)
{
    const long t = blockIdx.x * blockDim.x + threadIdx.x;   // 4 points per thread

    floatx4 p[3], u1[3], u2[3];
#pragma unroll
    for (int k = 0; k < 3; ++k) {
        p[k]  = pts[t * 3 + k];
        u1[k] = z1v[t * 3 + k];
        u2[k] = z2v[t * 3 + k];
    }
    const floatx4 s4 = sv[t];
    const floatx4 w4 = wv[t];

    // Output 0: fp32 pass-through copy of points (12 floats = 3 float4)
#pragma unroll
    for (int k = 0; k < 3; ++k) out[t * 3 + k] = p[k];

    floatx4 sres, wres;

#pragma unroll
    for (int j = 0; j < 4; ++j) {
        const int e = j * 3;
        const float z1x = GETF(u1, e), z1y = GETF(u1, e + 1), z1z = GETF(u1, e + 2);
        const float z2x = GETF(u2, e), z2y = GETF(u2, e + 1), z2z = GETF(u2, e + 2);
        const float px  = GETF(p,  e), py  = GETF(p,  e + 1), pz  = GETF(p,  e + 2);
        const float wf = w4[j];
        const float sf = s4[j];

        // base_dirs = z1 / ||z1||  (== x_col; re-normalizing a unit vector is identity)
        const float rn1 = rsqrtf(z1x * z1x + z1y * z1y + z1z * z1z);
        const float bx = z1x * rn1, by = z1y * rn1, bz = z1z * rn1;

        // approach_dirs = (z2 - <b,z2> b) / ||z2||
        const float inner = bx * z2x + by * z2y + bz * z2z;
        const float rn2 = rsqrtf(z2x * z2x + z2y * z2y + z2z * z2z);
        const float ax = (z2x - inner * bx) * rn2;
        const float ay = (z2y - inner * by) * rn2;
        const float az = (z2z - inner * bz) * rn2;

        // z_col = normalize(approach_dirs)
        const float rna = rsqrtf(ax * ax + ay * ay + az * az);
        const float zx = ax * rna, zy = ay * rna, zz = az * rna;

        // y_col = normalize(cross(z_col, x_col))
        const float cx = zy * bz - zz * by;
        const float cy = zz * bx - zx * bz;
        const float cz = zx * by - zy * bx;
        const float rnc = rsqrtf(cx * cx + cy * cy + cz * cz);
        const float yx = cx * rnc, yy = cy * rnc, yz = cz * rnc;

        // t_col = p + (w/2) x_col - gripper_depth * z_col   (raw w, pre-ReLU)
        const float tx = px + 0.5f * wf * bx - 0.1034f * zx;
        const float ty = py + 0.5f * wf * by - 0.1034f * zy;
        const float tz = pz + 0.5f * wf * bz - 0.1034f * zz;

        // grasp 4x4 row-major: row i = [x_i, y_i, z_i, t_i], bottom row [0,0,0,1]
        floatx4 g0, g1, g2, g3;
        g0[0] = bx; g0[1] = yx; g0[2] = zx; g0[3] = tx;
        g1[0] = by; g1[1] = yy; g1[2] = zy; g1[3] = ty;
        g2[0] = bz; g2[1] = yz; g2[2] = zz; g2[3] = tz;
        g3[0] = 0.f; g3[1] = 0.f; g3[2] = 0.f; g3[3] = 1.f;

        const long gb = GRASP_BASE4 + (t * 4 + j) * 4;
        out[gb + 0] = g0;
        out[gb + 1] = g1;
        out[gb + 2] = g2;
        out[gb + 3] = g3;

        sres[j] = 1.0f / (1.0f + __expf(-sf));
        wres[j] = fmaxf(wf, 0.0f);
    }

    out[S_BASE4 + t] = sres;
    out[W_BASE4 + t] = wres;
}

extern "C" void kernel_launch(void* const* d_in, const int* in_sizes, int n_in,
                              void* d_out, int out_size, void* d_ws, size_t ws_size,
                              hipStream_t stream) {
    const floatx4* pts = (const floatx4*)d_in[0];
    const floatx4* z1  = (const floatx4*)d_in[1];
    const floatx4* z2  = (const floatx4*)d_in[2];
    const floatx4* s   = (const floatx4*)d_in[3];
    const floatx4* w   = (const floatx4*)d_in[4];
    floatx4* out = (floatx4*)d_out;

    const int nthreads = (int)(N_POINTS / 4);   // 1048576
    const int block = 256;
    contactnet_kernel<<<nthreads / block, block, 0, stream>>>(pts, z1, z2, s, w, out);
}